// Round 2
// baseline (575.239 us; speedup 1.0000x reference)
//
#include <hip/hip_runtime.h>

typedef _Float16 f16;
typedef _Float16 f16x8 __attribute__((ext_vector_type(8)));
typedef float    f32x4 __attribute__((ext_vector_type(4)));

#define B_ 4
#define C_ 512
#define N_ 4096
#define M_ 64

// ---------------------------------------------------------------------------
// Kernel T: x [B][C][N] fp32  ->  x_t [B][N][C] f16   (LDS tile transpose)
// 256 threads (wave-structure-agnostic).
// ---------------------------------------------------------------------------
__global__ __launch_bounds__(256) void transpose_cast(
    const float* __restrict__ x, f16* __restrict__ xt)
{
    __shared__ float sT[64][65];   // 65: bank-conflict-free both directions
    const int n0 = blockIdx.x * 64;
    const int c0 = blockIdx.y * 64;
    const int b  = blockIdx.z;
    const int tid = threadIdx.x;

    #pragma unroll
    for (int i = 0; i < 16; ++i) {
        int e = i * 256 + tid;
        int c = e >> 6, n = e & 63;              // lanes: n consecutive -> coalesced
        sT[n][c] = x[((size_t)(b * C_ + c0 + c)) * N_ + (n0 + n)];
    }
    __syncthreads();
    #pragma unroll
    for (int i = 0; i < 16; ++i) {
        int e = i * 256 + tid;
        int n = e >> 6, c = e & 63;              // lanes: c consecutive -> coalesced
        xt[((size_t)(b * N_ + n0 + n)) * C_ + (c0 + c)] = (f16)sT[n][c];
    }
}

// ---------------------------------------------------------------------------
// Kernel A: fused qkv GEMM via mfma_f32_16x16x32_f16.
//   out[o][n] = sum_c W[o][c] * x[c][n],  oseg: 0=q 1=k 2..9=v(64-ch slices)
//   q_t [B][N][64] f16, k_t [B][N][64] f16, v [B][C][N] f16
// Block: 512 thr = 8 WAVES (wave=64!), tile 64o x 128n.
// wave w: ot16 = w&3 (o 16-slice), nhalf = w>>2 (n 64-half).
// ---------------------------------------------------------------------------
__global__ __launch_bounds__(512) void qkv_gemm(
    const f16* __restrict__ xt,
    const float* __restrict__ Wq, const float* __restrict__ bq,
    const float* __restrict__ Wk, const float* __restrict__ bk,
    const float* __restrict__ Wv, const float* __restrict__ bv,
    f16* __restrict__ qt, f16* __restrict__ kt, f16* __restrict__ vh)
{
    const int tid  = threadIdx.x;
    const int w    = tid >> 6;                   // 0..7
    const int lane = tid & 63;
    const int l15  = lane & 15;
    const int quad = lane >> 4;
    const int nBase = blockIdx.x * 128;
    const int oseg  = blockIdx.y;                // 0:q 1:k 2..9:v
    const int b     = blockIdx.z;
    const int ot16  = w & 3;
    const int nhalf = w >> 2;

    const float* Wsel;
    if (oseg == 0)      Wsel = Wq;
    else if (oseg == 1) Wsel = Wk;
    else                Wsel = Wv + (size_t)(oseg - 2) * 64 * C_;

    const int orow = ot16 * 16 + l15;            // A-frag m-row (local o)
    const float* wptr = Wsel + (size_t)orow * C_;

    f32x4 acc[4] = {};

    for (int c0 = 0; c0 < C_; c0 += 32) {
        // A fragment: W[orow][c0 + quad*8 + j], fp32 -> f16
        f16x8 a8;
        {
            const float4 w0 = *(const float4*)(wptr + c0 + quad * 8);
            const float4 w1 = *(const float4*)(wptr + c0 + quad * 8 + 4);
            a8[0]=(f16)w0.x; a8[1]=(f16)w0.y; a8[2]=(f16)w0.z; a8[3]=(f16)w0.w;
            a8[4]=(f16)w1.x; a8[5]=(f16)w1.y; a8[6]=(f16)w1.z; a8[7]=(f16)w1.w;
        }
        #pragma unroll
        for (int ns = 0; ns < 4; ++ns) {
            int n = nBase + nhalf * 64 + ns * 16 + l15;
            f16x8 b8 = *(const f16x8*)(xt + ((size_t)(b * N_ + n)) * C_ + c0 + quad * 8);
            acc[ns] = __builtin_amdgcn_mfma_f32_16x16x32_f16(a8, b8, acc[ns], 0, 0, 0);
        }
    }

    // Epilogue. C/D layout: row = quad*4 + r (local m), col = l15 (local n).
    #pragma unroll
    for (int ns = 0; ns < 4; ++ns) {
        int n = nBase + nhalf * 64 + ns * 16 + l15;
        #pragma unroll
        for (int r = 0; r < 4; ++r) {
            int olocal = ot16 * 16 + quad * 4 + r;
            float bias;
            if (oseg == 0)      bias = bq[olocal];
            else if (oseg == 1) bias = bk[olocal];
            else                bias = bv[(oseg - 2) * 64 + olocal];
            f16 h = (f16)(acc[ns][r] + bias);
            if (oseg == 0) {
                qt[((size_t)(b * N_ + n)) * M_ + olocal] = h;
            } else if (oseg == 1) {
                kt[((size_t)(b * N_ + n)) * M_ + olocal] = h;
            } else {
                int c = (oseg - 2) * 64 + olocal;
                vh[((size_t)(b * C_ + c)) * N_ + n] = h;
            }
        }
    }
}

// ---------------------------------------------------------------------------
// Kernel B: flash attention + gamma*feat + x residual.
// Block: 512 thr = 8 WAVES, TI=32 queries, TJ=64 keys/iter.
// Scores: wave = (ihalf w&1) x (jq w>>1 in 0..3), one 16x16 tile, K=64.
// Softmax: 64 lanes, half-row each, __shfl_xor(32) combine.
// PV:     wave = 64-channel slice (w*64 covers all 512 ch); 2x4 acc tiles.
// ---------------------------------------------------------------------------
__global__ __launch_bounds__(512) void attn(
    const f16* __restrict__ qt, const f16* __restrict__ kt,
    const f16* __restrict__ vh, const float* __restrict__ x,
    const float* __restrict__ gamma, float* __restrict__ out)
{
    __shared__ __align__(16) float sP[32][68];   // 272B rows: 16B-aligned
    __shared__ __align__(16) float sM[32];
    __shared__ __align__(16) float sL[32];
    __shared__ __align__(16) float sAlpha[32];

    const int tid  = threadIdx.x;
    const int w    = tid >> 6;                   // 0..7
    const int lane = tid & 63;
    const int l15  = lane & 15;
    const int quad = lane >> 4;
    const int b    = blockIdx.y;
    const int i0   = blockIdx.x * 32;

    const int ihalf_s = w & 1;   // score-phase i-half
    const int jq      = w >> 1;  // score-phase j-quarter (0..3)
    const int c0w     = w * 64;  // PV channel slice (0..448)

    // Preload q A-fragments for this wave's score i-half (block-invariant).
    f16x8 aq[2];
    #pragma unroll
    for (int kh = 0; kh < 2; ++kh) {
        int i = i0 + ihalf_s * 16 + l15;
        aq[kh] = *(const f16x8*)(qt + ((size_t)(b * N_ + i)) * M_ + kh * 32 + quad * 8);
    }

    if (tid < 32) { sM[tid] = -__builtin_inff(); sL[tid] = 0.f; }
    f32x4 acc[2][4] = {};
    __syncthreads();

    for (int j0 = 0; j0 < N_; j0 += 64) {
        // ---- scores: S[i][j] = sum_m q[m,i] k[m,j] ----
        {
            f32x4 s = {};
            #pragma unroll
            for (int kh = 0; kh < 2; ++kh) {
                int j = j0 + jq * 16 + l15;
                f16x8 bk8 = *(const f16x8*)(kt + ((size_t)(b * N_ + j)) * M_ + kh * 32 + quad * 8);
                s = __builtin_amdgcn_mfma_f32_16x16x32_f16(aq[kh], bk8, s, 0, 0, 0);
            }
            #pragma unroll
            for (int r = 0; r < 4; ++r)
                sP[ihalf_s * 16 + quad * 4 + r][jq * 16 + l15] = s[r];
        }
        __syncthreads();

        // ---- online softmax: 64 lanes, row = tid&31, half-row each ----
        if (tid < 64) {
            const int row  = tid & 31;
            const int joff = (tid >> 5) * 32;    // 0 or 32
            float mold = sM[row];
            float mt = -__builtin_inff();
            #pragma unroll 8
            for (int jj = 0; jj < 32; ++jj) mt = fmaxf(mt, sP[row][joff + jj]);
            mt = fmaxf(mt, __shfl_xor(mt, 32, 64));   // combine halves
            float mnew  = fmaxf(mold, mt);
            float sum = 0.f;
            #pragma unroll 8
            for (int jj = 0; jj < 32; ++jj) {
                float e = __expf(sP[row][joff + jj] - mnew);
                sP[row][joff + jj] = e;
                sum += e;
            }
            sum += __shfl_xor(sum, 32, 64);
            if (joff == 0) {
                float alpha = __expf(mold - mnew);
                sL[row]     = sL[row] * alpha + sum;
                sM[row]     = mnew;
                sAlpha[row] = alpha;
            }
        }
        __syncthreads();

        // ---- PV: feat[i][c] += P[i][j] * v[c][j] ----
        f16x8 pa[2][2];
        #pragma unroll
        for (int ih = 0; ih < 2; ++ih) {
            #pragma unroll
            for (int kh = 0; kh < 2; ++kh) {
                const float4 p0 = *(const float4*)&sP[ih * 16 + l15][kh * 32 + quad * 8];
                const float4 p1 = *(const float4*)&sP[ih * 16 + l15][kh * 32 + quad * 8 + 4];
                f16x8 t;
                t[0]=(f16)p0.x; t[1]=(f16)p0.y; t[2]=(f16)p0.z; t[3]=(f16)p0.w;
                t[4]=(f16)p1.x; t[5]=(f16)p1.y; t[6]=(f16)p1.z; t[7]=(f16)p1.w;
                pa[ih][kh] = t;
            }
            // rescale accumulators by alpha (rows = quad*4 + r in C-layout)
            float4 av = *(const float4*)&sAlpha[ih * 16 + quad * 4];
            #pragma unroll
            for (int ct = 0; ct < 4; ++ct) {
                acc[ih][ct][0] *= av.x; acc[ih][ct][1] *= av.y;
                acc[ih][ct][2] *= av.z; acc[ih][ct][3] *= av.w;
            }
        }
        #pragma unroll
        for (int ct = 0; ct < 4; ++ct) {
            int c = c0w + ct * 16 + l15;
            #pragma unroll
            for (int kh = 0; kh < 2; ++kh) {
                f16x8 vb = *(const f16x8*)(vh + ((size_t)(b * C_ + c)) * N_ + j0 + kh * 32 + quad * 8);
                acc[0][ct] = __builtin_amdgcn_mfma_f32_16x16x32_f16(pa[0][kh], vb, acc[0][ct], 0, 0, 0);
                acc[1][ct] = __builtin_amdgcn_mfma_f32_16x16x32_f16(pa[1][kh], vb, acc[1][ct], 0, 0, 0);
            }
        }
        __syncthreads();   // protect sP before next tile's score writes
    }

    // ---- epilogue: out = gamma * feat / l + x ----
    const float g = gamma[0];
    #pragma unroll
    for (int ih = 0; ih < 2; ++ih) {
        float4 lv = *(const float4*)&sL[ih * 16 + quad * 4];
        float linv[4] = {1.f / lv.x, 1.f / lv.y, 1.f / lv.z, 1.f / lv.w};
        #pragma unroll
        for (int ct = 0; ct < 4; ++ct) {
            int c = c0w + ct * 16 + l15;
            #pragma unroll
            for (int r = 0; r < 4; ++r) {
                int i = i0 + ih * 16 + quad * 4 + r;
                size_t idx = ((size_t)(b * C_ + c)) * N_ + i;
                out[idx] = g * (acc[ih][ct][r] * linv[r]) + x[idx];
            }
        }
    }
}

// ---------------------------------------------------------------------------
extern "C" void kernel_launch(void* const* d_in, const int* in_sizes, int n_in,
                              void* d_out, int out_size, void* d_ws, size_t ws_size,
                              hipStream_t stream)
{
    const float* x     = (const float*)d_in[0];
    const float* Wq    = (const float*)d_in[1];
    const float* bq    = (const float*)d_in[2];
    const float* Wk    = (const float*)d_in[3];
    const float* bk    = (const float*)d_in[4];
    const float* Wv    = (const float*)d_in[5];
    const float* bv    = (const float*)d_in[6];
    const float* gamma = (const float*)d_in[7];
    float* out = (float*)d_out;

    char* ws = (char*)d_ws;
    f16* xt = (f16*)ws;                                   // B*N*C   (16 MB)
    f16* qt = (f16*)(ws + (size_t)B_ * N_ * C_ * 2);      // B*N*M   ( 2 MB)
    f16* kt = qt + (size_t)B_ * N_ * M_;                  // B*N*M   ( 2 MB)
    f16* vh = kt + (size_t)B_ * N_ * M_;                  // B*C*N   (16 MB)

    transpose_cast<<<dim3(N_ / 64, C_ / 64, B_), 256, 0, stream>>>(x, xt);
    qkv_gemm<<<dim3(N_ / 128, 10, B_), 512, 0, stream>>>(
        xt, Wq, bq, Wk, bk, Wv, bv, qt, kt, vh);
    attn<<<dim3(N_ / 32, B_), 512, 0, stream>>>(qt, kt, vh, x, gamma, out);
}